// Round 1
// baseline (1177.872 us; speedup 1.0000x reference)
//
#include <hip/hip_runtime.h>
#include <hip/hip_bf16.h>
#include <math.h>

#define N_NODES 100000
#define N_EDGES 3200000
#define HIDDEN 32
#define K_TOP 35
#define NPG 100
#define N_GRAPHS 1000

// ---------------- CSR build ----------------

__global__ void k_init(int* cnt, int* cnt2) {
    int i = blockIdx.x * 256 + threadIdx.x;
    if (i < N_NODES) { cnt[i] = 0; cnt2[i] = 0; }
}

__global__ void k_count(const int* __restrict__ dst, int* __restrict__ cnt) {
    int e = blockIdx.x * 256 + threadIdx.x;
    if (e < N_EDGES) atomicAdd(&cnt[dst[e]], 1);
}

__global__ void k_dis(const int* __restrict__ cnt, float* __restrict__ dis) {
    int i = blockIdx.x * 256 + threadIdx.x;
    if (i < N_NODES) dis[i] = 1.0f / sqrtf((float)(cnt[i] + 1));  // deg incl self-loop
}

// block scans 1024 elems (256 thr x 4); writes block-inclusive scan into row_ptr
__global__ void k_scanA(const int* __restrict__ cnt, int* __restrict__ row_ptr,
                        int* __restrict__ bsums) {
    __shared__ int sd[256];
    int t = threadIdx.x, b = blockIdx.x;
    int base = b * 1024 + t * 4;
    int v[4]; int s = 0;
#pragma unroll
    for (int i = 0; i < 4; i++) {
        int g = base + i;
        int x = (g < N_NODES) ? cnt[g] : 0;
        s += x; v[i] = s;
    }
    sd[t] = s; __syncthreads();
    int mysum = s;
    for (int off = 1; off < 256; off <<= 1) {
        int x = (t >= off) ? sd[t - off] : 0;
        __syncthreads();
        sd[t] += x;
        __syncthreads();
    }
    int excl = sd[t] - mysum;
#pragma unroll
    for (int i = 0; i < 4; i++) {
        int g = base + i;
        if (g < N_NODES) row_ptr[g] = excl + v[i];
    }
    if (t == 255) bsums[b] = sd[255];
}

// exclusive scan of 98 block sums, single block of 128 threads
__global__ void k_scanB(int* __restrict__ bsums) {
    __shared__ int sd[128];
    int t = threadIdx.x;
    int v = (t < 98) ? bsums[t] : 0;
    sd[t] = v; __syncthreads();
    for (int off = 1; off < 128; off <<= 1) {
        int x = (t >= off) ? sd[t - off] : 0;
        __syncthreads();
        sd[t] += x;
        __syncthreads();
    }
    if (t < 98) bsums[t] = sd[t] - v;
}

// convert block-inclusive to global-exclusive row_ptr
__global__ void k_scanC(const int* __restrict__ cnt, const int* __restrict__ bsums,
                        int* __restrict__ row_ptr) {
    int i = blockIdx.x * 256 + threadIdx.x;
    if (i < N_NODES) row_ptr[i] = row_ptr[i] - cnt[i] + bsums[i >> 10];
}

__global__ void k_fill(const int* __restrict__ src, const int* __restrict__ dst,
                       const int* __restrict__ row_ptr, int* __restrict__ cnt2,
                       int* __restrict__ csr_src) {
    int e = blockIdx.x * 256 + threadIdx.x;
    if (e < N_EDGES) {
        int d = dst[e];
        int pos = atomicAdd(&cnt2[d], 1);
        csr_src[row_ptr[d] + pos] = src[e];
    }
}

// ---------------- GCN layer ----------------

// hs[n][o] = dis[n] * sum_c in[n*128+col_off+c] * w[c*32+o]
template <int INF>
__global__ void k_mm(const float* __restrict__ in, int col_off,
                     const float* __restrict__ w, const float* __restrict__ dis,
                     float* __restrict__ hs) {
    __shared__ float wl[INF * HIDDEN];
    int t = threadIdx.x;
    for (int i = t; i < INF * HIDDEN; i += 256) wl[i] = w[i];
    __syncthreads();
    int n = blockIdx.x * 256 + t;
    if (n >= N_NODES) return;
    const float* row = in + (size_t)n * 128 + col_off;
    float acc[HIDDEN];
#pragma unroll
    for (int o = 0; o < HIDDEN; o++) acc[o] = 0.f;
    for (int c4 = 0; c4 < INF / 4; c4++) {
        float4 v = *(const float4*)(row + c4 * 4);
        float xv[4] = {v.x, v.y, v.z, v.w};
#pragma unroll
        for (int k = 0; k < 4; k++) {
            const float* wr = &wl[(c4 * 4 + k) * HIDDEN];
#pragma unroll
            for (int o = 0; o < HIDDEN; o++) acc[o] += xv[k] * wr[o];
        }
    }
    float d = dis[n];
    float4* o4 = (float4*)(hs + (size_t)n * HIDDEN);
#pragma unroll
    for (int q = 0; q < HIDDEN / 4; q++)
        o4[q] = make_float4(acc[4 * q] * d, acc[4 * q + 1] * d,
                            acc[4 * q + 2] * d, acc[4 * q + 3] * d);
}

// out[n][col_off+c] = tanh(dis[n]*(hs[n][c] + sum_in hs[src][c]) + b[c])
__global__ void k_agg(const float* __restrict__ hs, const float* __restrict__ dis,
                      const int* __restrict__ row_ptr, const int* __restrict__ cnt,
                      const int* __restrict__ csr_src, const float* __restrict__ bias,
                      float* __restrict__ feat, int col_off) {
    int t = blockIdx.x * 256 + threadIdx.x;
    int n = t >> 5;
    int c = t & 31;
    if (n >= N_NODES) return;
    int start = row_ptr[n];
    int m = cnt[n];
    float sum = hs[(size_t)n * HIDDEN + c];
    for (int j = 0; j < m; j++) {
        int s = csr_src[start + j];
        sum += hs[(size_t)s * HIDDEN + c];
    }
    feat[(size_t)n * 128 + col_off + c] = tanhf(dis[n] * sum + bias[c]);
}

// ---------------- sort-pool + head (one block per graph) ----------------

__global__ void k_head(const float* __restrict__ feat,
                       const float* __restrict__ c1w, const float* __restrict__ c1b,
                       const float* __restrict__ c2w, const float* __restrict__ c2b,
                       const float* __restrict__ f1w, const float* __restrict__ f1b,
                       const float* __restrict__ f2w, const float* __restrict__ f2b,
                       float* __restrict__ out) {
    __shared__ float vals[NPG];
    __shared__ int sel[K_TOP];
    __shared__ float tk[K_TOP][129];
    __shared__ float y1[16][K_TOP];
    __shared__ float y2[16][17];
    __shared__ float y3[416];
    __shared__ float y4[128];
    __shared__ float r2[128];
    int g = blockIdx.x, t = threadIdx.x;
    const float* fg = feat + (size_t)g * NPG * 128;

    if (t < NPG) vals[t] = fg[t * 128 + 127];
    __syncthreads();
    // stable descending rank (matches stable argsort(-v))
    if (t < NPG) {
        float v = vals[t];
        int r = 0;
        for (int j = 0; j < NPG; j++) {
            float u = vals[j];
            r += (u > v) || (u == v && j < t);
        }
        if (r < K_TOP) sel[r] = t;
    }
    __syncthreads();
    for (int i = t; i < K_TOP * 128; i += 256) {
        int k = i >> 7, c = i & 127;
        tk[k][c] = fg[sel[k] * 128 + c];
    }
    __syncthreads();
    // conv1 (1x1): y1[o][k] = relu(b + sum_c w[o,c]*tk[k][c])
    for (int i = t; i < 16 * K_TOP; i += 256) {
        int o = i & 15, k = i >> 4;
        float s = c1b[o];
        const float* wr = c1w + o * 128;
#pragma unroll 8
        for (int c = 0; c < 128; c++) s += wr[c] * tk[k][c];
        y1[o][k] = fmaxf(s, 0.f);
    }
    __syncthreads();
    // maxpool1d(2): 35 -> 17
    for (int i = t; i < 16 * 17; i += 256) {
        int o = i & 15, l = i >> 4;
        y2[o][l] = fmaxf(y1[o][2 * l], y1[o][2 * l + 1]);
    }
    __syncthreads();
    // conv2 (k=5, VALID): [16,17] -> [32,13]
    for (int idx = t; idx < 32 * 13; idx += 256) {
        int o2 = idx / 13, tt = idx - o2 * 13;
        float s = c2b[o2];
        const float* wr = c2w + o2 * 80;
#pragma unroll
        for (int i = 0; i < 16; i++)
#pragma unroll
            for (int j = 0; j < 5; j++) s += wr[i * 5 + j] * y2[i][tt + j];
        y3[idx] = fmaxf(s, 0.f);
    }
    __syncthreads();
    // fc1: 416 -> 128
    if (t < 128) {
        float s = f1b[t];
        const float* wr = f1w + t * 416;
        for (int i = 0; i < 416; i++) s += wr[i] * y3[i];
        y4[t] = fmaxf(s, 0.f);
    }
    __syncthreads();
    if (t < 128) r2[t] = f2w[t] * y4[t];
    __syncthreads();
    for (int off = 64; off > 0; off >>= 1) {
        if (t < off) r2[t] += r2[t + off];
        __syncthreads();
    }
    if (t == 0) out[g] = 1.0f / (1.0f + expf(-(r2[0] + f2b[0])));
}

// ---------------- launch ----------------

static inline size_t alignup(size_t x) { return (x + 255) & ~(size_t)255; }

extern "C" void kernel_launch(void* const* d_in, const int* in_sizes, int n_in,
                              void* d_out, int out_size, void* d_ws, size_t ws_size,
                              hipStream_t stream) {
    const float* x     = (const float*)d_in[0];
    const int*   ei    = (const int*)d_in[1];
    const int*   srcp  = ei;
    const int*   dstp  = ei + N_EDGES;
    // d_in[2] = batch (unused: graphs are contiguous blocks of 100)
    const float* w0 = (const float*)d_in[3];
    const float* b0 = (const float*)d_in[4];
    const float* w1 = (const float*)d_in[5];
    const float* b1 = (const float*)d_in[6];
    const float* w2 = (const float*)d_in[7];
    const float* b2 = (const float*)d_in[8];
    const float* w3 = (const float*)d_in[9];
    const float* b3 = (const float*)d_in[10];
    const float* c1w = (const float*)d_in[11];
    const float* c1b = (const float*)d_in[12];
    const float* c2w = (const float*)d_in[13];
    const float* c2b = (const float*)d_in[14];
    const float* f1w = (const float*)d_in[15];
    const float* f1b = (const float*)d_in[16];
    const float* f2w = (const float*)d_in[17];
    const float* f2b = (const float*)d_in[18];
    float* out = (float*)d_out;

    char* p = (char*)d_ws;
    int* cnt     = (int*)p;   p += alignup(sizeof(int) * N_NODES);
    int* cnt2    = (int*)p;   p += alignup(sizeof(int) * N_NODES);
    int* row_ptr = (int*)p;   p += alignup(sizeof(int) * (N_NODES + 1));
    int* bsums   = (int*)p;   p += alignup(sizeof(int) * 256);
    float* dis   = (float*)p; p += alignup(sizeof(float) * N_NODES);
    int* csr     = (int*)p;   p += alignup(sizeof(int) * N_EDGES);
    float* hs    = (float*)p; p += alignup(sizeof(float) * (size_t)N_NODES * HIDDEN);
    float* feat  = (float*)p; p += alignup(sizeof(float) * (size_t)N_NODES * 128);

    const int NB_N = (N_NODES + 255) / 256;        // 391
    const int NB_E = (N_EDGES + 255) / 256;        // 12500
    const int NB_S = (N_NODES + 1023) / 1024;      // 98
    const int NB_A = ((N_NODES * 32) + 255) / 256; // 12500

    k_init<<<NB_N, 256, 0, stream>>>(cnt, cnt2);
    k_count<<<NB_E, 256, 0, stream>>>(dstp, cnt);
    k_dis<<<NB_N, 256, 0, stream>>>(cnt, dis);
    k_scanA<<<NB_S, 256, 0, stream>>>(cnt, row_ptr, bsums);
    k_scanB<<<1, 128, 0, stream>>>(bsums);
    k_scanC<<<NB_N, 256, 0, stream>>>(cnt, bsums, row_ptr);
    k_fill<<<NB_E, 256, 0, stream>>>(srcp, dstp, row_ptr, cnt2, csr);

    // layer 0: in = x (128 feats), out -> feat cols [0,32)
    k_mm<128><<<NB_N, 256, 0, stream>>>(x, 0, w0, dis, hs);
    k_agg<<<NB_A, 256, 0, stream>>>(hs, dis, row_ptr, cnt, csr, b0, feat, 0);
    // layer 1: in = feat cols [0,32), out -> [32,64)
    k_mm<32><<<NB_N, 256, 0, stream>>>(feat, 0, w1, dis, hs);
    k_agg<<<NB_A, 256, 0, stream>>>(hs, dis, row_ptr, cnt, csr, b1, feat, 32);
    // layer 2
    k_mm<32><<<NB_N, 256, 0, stream>>>(feat, 32, w2, dis, hs);
    k_agg<<<NB_A, 256, 0, stream>>>(hs, dis, row_ptr, cnt, csr, b2, feat, 64);
    // layer 3
    k_mm<32><<<NB_N, 256, 0, stream>>>(feat, 64, w3, dis, hs);
    k_agg<<<NB_A, 256, 0, stream>>>(hs, dis, row_ptr, cnt, csr, b3, feat, 96);

    k_head<<<N_GRAPHS, 256, 0, stream>>>(feat, c1w, c1b, c2w, c2b,
                                         f1w, f1b, f2w, f2b, out);
}

// Round 2
// 659.049 us; speedup vs baseline: 1.7872x; 1.7872x over previous
//
#include <hip/hip_runtime.h>
#include <hip/hip_bf16.h>
#include <math.h>

#define N_NODES 100000
#define N_EDGES 3200000
#define HIDDEN 32
#define K_TOP 35
#define NPG 100
#define N_GRAPHS 1000

#define BSHIFT 9
#define NLOC 512                    // nodes per bucket
#define NBUCK 196                   // ceil(100000/512)
#define BIN_BLOCKS 256
#define BIN_CHUNK 49                // 256 blocks * 256 thr * 49 >= 3.2M

// ---------------- CSR build: two-level counting sort ----------------

__global__ void k_hist(const int* __restrict__ dst, int* __restrict__ bcnt) {
    __shared__ int h[NBUCK];
    int t = threadIdx.x;
    for (int i = t; i < NBUCK; i += 256) h[i] = 0;
    __syncthreads();
    int base = blockIdx.x * (256 * BIN_CHUNK);
    for (int k = 0; k < BIN_CHUNK; k++) {
        int e = base + k * 256 + t;
        if (e < N_EDGES) atomicAdd(&h[dst[e] >> BSHIFT], 1);
    }
    __syncthreads();
    for (int i = t; i < NBUCK; i += 256) if (h[i]) atomicAdd(&bcnt[i], h[i]);
}

// exclusive scan of the 196 bucket counts; init cursors
__global__ void k_bscan(const int* __restrict__ bcnt, int* __restrict__ bbase,
                        int* __restrict__ bcur) {
    __shared__ int sd[256];
    int t = threadIdx.x;
    int v = (t < NBUCK) ? bcnt[t] : 0;
    sd[t] = v; __syncthreads();
    for (int off = 1; off < 256; off <<= 1) {
        int x = (t >= off) ? sd[t - off] : 0;
        __syncthreads();
        sd[t] += x;
        __syncthreads();
    }
    int excl = sd[t] - v;
    if (t < NBUCK) { bbase[t] = excl; bcur[t] = excl; }
    if (t == NBUCK - 1) bbase[NBUCK] = excl + v;
}

// bin edges into bucket-contiguous (src,dst) arrays
__global__ void k_bin(const int* __restrict__ src, const int* __restrict__ dst,
                      int* __restrict__ bcur, int* __restrict__ bsrc,
                      int* __restrict__ bdst) {
    __shared__ int h[NBUCK];
    __shared__ int lbase[NBUCK];
    __shared__ int lcur[NBUCK];
    int t = threadIdx.x;
    for (int i = t; i < NBUCK; i += 256) { h[i] = 0; lcur[i] = 0; }
    __syncthreads();
    int base = blockIdx.x * (256 * BIN_CHUNK);
    for (int k = 0; k < BIN_CHUNK; k++) {
        int e = base + k * 256 + t;
        if (e < N_EDGES) atomicAdd(&h[dst[e] >> BSHIFT], 1);
    }
    __syncthreads();
    for (int i = t; i < NBUCK; i += 256)
        lbase[i] = h[i] ? atomicAdd(&bcur[i], h[i]) : 0;
    __syncthreads();
    for (int k = 0; k < BIN_CHUNK; k++) {
        int e = base + k * 256 + t;
        if (e < N_EDGES) {
            int s = src[e], d = dst[e];
            int bk = d >> BSHIFT;
            int pos = atomicAdd(&lcur[bk], 1);
            int idx = lbase[bk] + pos;
            bsrc[idx] = s;
            bdst[idx] = d;
        }
    }
}

// per-bucket node counts + within-bucket scan -> cnt, row_ptr, dis (no global atomics)
__global__ void k_cnt(const int* __restrict__ bdst, const int* __restrict__ bbase,
                      int* __restrict__ cnt, int* __restrict__ row_ptr,
                      float* __restrict__ dis) {
    __shared__ int h[NLOC];
    __shared__ int sd[256];
    int b = blockIdx.x, t = threadIdx.x;
    h[t] = 0; h[t + 256] = 0;
    __syncthreads();
    int r0 = bbase[b], r1 = bbase[b + 1];
    for (int i = r0 + t; i < r1; i += 256)
        atomicAdd(&h[bdst[i] & (NLOC - 1)], 1);
    __syncthreads();
    int a0 = h[2 * t], a1 = h[2 * t + 1];
    int ps = a0 + a1;
    sd[t] = ps; __syncthreads();
    for (int off = 1; off < 256; off <<= 1) {
        int x = (t >= off) ? sd[t - off] : 0;
        __syncthreads();
        sd[t] += x;
        __syncthreads();
    }
    int excl = sd[t] - ps;
    int n0 = (b << BSHIFT) + 2 * t;
    if (n0 < N_NODES) {
        cnt[n0] = a0;
        dis[n0] = rsqrtf((float)(a0 + 1));
        row_ptr[n0] = r0 + excl;
    }
    int n1 = n0 + 1;
    if (n1 < N_NODES) {
        cnt[n1] = a1;
        dis[n1] = rsqrtf((float)(a1 + 1));
        row_ptr[n1] = r0 + excl + a0;
    }
}

// per-bucket CSR fill; all writes land in one ~64KB L2-resident region
__global__ void k_csrfill(const int* __restrict__ bsrc, const int* __restrict__ bdst,
                          const int* __restrict__ bbase, const int* __restrict__ row_ptr,
                          int* __restrict__ csr) {
    __shared__ int rp[NLOC];
    __shared__ int cur[NLOC];
    int b = blockIdx.x, t = threadIdx.x;
    int node = (b << BSHIFT) + t;
    rp[t] = (node < N_NODES) ? row_ptr[node] : 0;
    cur[t] = 0;
    __syncthreads();
    int r0 = bbase[b], r1 = bbase[b + 1];
    for (int i = r0 + t; i < r1; i += NLOC) {
        int s = bsrc[i], d = bdst[i];
        int loc = d & (NLOC - 1);
        int pos = atomicAdd(&cur[loc], 1);
        csr[rp[loc] + pos] = s;
    }
}

// ---------------- GCN layer ----------------

// hs[n][o] = dis[n] * sum_c in[n*128+col_off+c] * w[c*32+o]
template <int INF>
__global__ void k_mm(const float* __restrict__ in, int col_off,
                     const float* __restrict__ w, const float* __restrict__ dis,
                     float* __restrict__ hs) {
    __shared__ float wl[INF * HIDDEN];
    int t = threadIdx.x;
    for (int i = t; i < INF * HIDDEN; i += 256) wl[i] = w[i];
    __syncthreads();
    int n = blockIdx.x * 256 + t;
    if (n >= N_NODES) return;
    const float* row = in + (size_t)n * 128 + col_off;
    float acc[HIDDEN];
#pragma unroll
    for (int o = 0; o < HIDDEN; o++) acc[o] = 0.f;
    for (int c4 = 0; c4 < INF / 4; c4++) {
        float4 v = *(const float4*)(row + c4 * 4);
        float xv[4] = {v.x, v.y, v.z, v.w};
#pragma unroll
        for (int k = 0; k < 4; k++) {
            const float* wr = &wl[(c4 * 4 + k) * HIDDEN];
#pragma unroll
            for (int o = 0; o < HIDDEN; o++) acc[o] += xv[k] * wr[o];
        }
    }
    float d = dis[n];
    float4* o4 = (float4*)(hs + (size_t)n * HIDDEN);
#pragma unroll
    for (int q = 0; q < HIDDEN / 4; q++)
        o4[q] = make_float4(acc[4 * q] * d, acc[4 * q + 1] * d,
                            acc[4 * q + 2] * d, acc[4 * q + 3] * d);
}

// out[n][col_off+c] = tanh(dis[n]*(hs[n][c] + sum_in hs[src][c]) + b[c])
__global__ void k_agg(const float* __restrict__ hs, const float* __restrict__ dis,
                      const int* __restrict__ row_ptr, const int* __restrict__ cnt,
                      const int* __restrict__ csr_src, const float* __restrict__ bias,
                      float* __restrict__ feat, int col_off) {
    int t = blockIdx.x * 256 + threadIdx.x;
    int n = t >> 5;
    int c = t & 31;
    if (n >= N_NODES) return;
    int start = row_ptr[n];
    int m = cnt[n];
    float sum = hs[(size_t)n * HIDDEN + c];
    float s0 = 0.f, s1 = 0.f, s2 = 0.f, s3 = 0.f;
    int j = 0;
    for (; j + 3 < m; j += 4) {
        int i0 = csr_src[start + j];
        int i1 = csr_src[start + j + 1];
        int i2 = csr_src[start + j + 2];
        int i3 = csr_src[start + j + 3];
        s0 += hs[(size_t)i0 * HIDDEN + c];
        s1 += hs[(size_t)i1 * HIDDEN + c];
        s2 += hs[(size_t)i2 * HIDDEN + c];
        s3 += hs[(size_t)i3 * HIDDEN + c];
    }
    for (; j < m; j++) sum += hs[(size_t)csr_src[start + j] * HIDDEN + c];
    sum += (s0 + s1) + (s2 + s3);
    feat[(size_t)n * 128 + col_off + c] = tanhf(dis[n] * sum + bias[c]);
}

// ---------------- sort-pool + head (one block per graph) ----------------

__global__ void k_head(const float* __restrict__ feat,
                       const float* __restrict__ c1w, const float* __restrict__ c1b,
                       const float* __restrict__ c2w, const float* __restrict__ c2b,
                       const float* __restrict__ f1w, const float* __restrict__ f1b,
                       const float* __restrict__ f2w, const float* __restrict__ f2b,
                       float* __restrict__ out) {
    __shared__ float vals[NPG];
    __shared__ int sel[K_TOP];
    __shared__ float tk[K_TOP][129];
    __shared__ float y1[16][K_TOP];
    __shared__ float y2[16][17];
    __shared__ float y3[416];
    __shared__ float y4[128];
    __shared__ float r2[128];
    int g = blockIdx.x, t = threadIdx.x;
    const float* fg = feat + (size_t)g * NPG * 128;

    if (t < NPG) vals[t] = fg[t * 128 + 127];
    __syncthreads();
    // stable descending rank (matches stable argsort(-v))
    if (t < NPG) {
        float v = vals[t];
        int r = 0;
        for (int j = 0; j < NPG; j++) {
            float u = vals[j];
            r += (u > v) || (u == v && j < t);
        }
        if (r < K_TOP) sel[r] = t;
    }
    __syncthreads();
    for (int i = t; i < K_TOP * 128; i += 256) {
        int k = i >> 7, c = i & 127;
        tk[k][c] = fg[sel[k] * 128 + c];
    }
    __syncthreads();
    // conv1 (1x1): y1[o][k] = relu(b + sum_c w[o,c]*tk[k][c])
    for (int i = t; i < 16 * K_TOP; i += 256) {
        int o = i & 15, k = i >> 4;
        float s = c1b[o];
        const float* wr = c1w + o * 128;
#pragma unroll 8
        for (int c = 0; c < 128; c++) s += wr[c] * tk[k][c];
        y1[o][k] = fmaxf(s, 0.f);
    }
    __syncthreads();
    // maxpool1d(2): 35 -> 17
    for (int i = t; i < 16 * 17; i += 256) {
        int o = i & 15, l = i >> 4;
        y2[o][l] = fmaxf(y1[o][2 * l], y1[o][2 * l + 1]);
    }
    __syncthreads();
    // conv2 (k=5, VALID): [16,17] -> [32,13]
    for (int idx = t; idx < 32 * 13; idx += 256) {
        int o2 = idx / 13, tt = idx - o2 * 13;
        float s = c2b[o2];
        const float* wr = c2w + o2 * 80;
#pragma unroll
        for (int i = 0; i < 16; i++)
#pragma unroll
            for (int j = 0; j < 5; j++) s += wr[i * 5 + j] * y2[i][tt + j];
        y3[idx] = fmaxf(s, 0.f);
    }
    __syncthreads();
    // fc1: 416 -> 128
    if (t < 128) {
        float s = f1b[t];
        const float* wr = f1w + t * 416;
        for (int i = 0; i < 416; i++) s += wr[i] * y3[i];
        y4[t] = fmaxf(s, 0.f);
    }
    __syncthreads();
    if (t < 128) r2[t] = f2w[t] * y4[t];
    __syncthreads();
    for (int off = 64; off > 0; off >>= 1) {
        if (t < off) r2[t] += r2[t + off];
        __syncthreads();
    }
    if (t == 0) out[g] = 1.0f / (1.0f + expf(-(r2[0] + f2b[0])));
}

// ---------------- launch ----------------

static inline size_t alignup(size_t x) { return (x + 255) & ~(size_t)255; }

extern "C" void kernel_launch(void* const* d_in, const int* in_sizes, int n_in,
                              void* d_out, int out_size, void* d_ws, size_t ws_size,
                              hipStream_t stream) {
    const float* x    = (const float*)d_in[0];
    const int*   ei   = (const int*)d_in[1];
    const int*   srcp = ei;
    const int*   dstp = ei + N_EDGES;
    const float* w0 = (const float*)d_in[3];
    const float* b0 = (const float*)d_in[4];
    const float* w1 = (const float*)d_in[5];
    const float* b1 = (const float*)d_in[6];
    const float* w2 = (const float*)d_in[7];
    const float* b2 = (const float*)d_in[8];
    const float* w3 = (const float*)d_in[9];
    const float* b3 = (const float*)d_in[10];
    const float* c1w = (const float*)d_in[11];
    const float* c1b = (const float*)d_in[12];
    const float* c2w = (const float*)d_in[13];
    const float* c2b = (const float*)d_in[14];
    const float* f1w = (const float*)d_in[15];
    const float* f1b = (const float*)d_in[16];
    const float* f2w = (const float*)d_in[17];
    const float* f2b = (const float*)d_in[18];
    float* out = (float*)d_out;

    char* p = (char*)d_ws;
    int* cnt     = (int*)p; p += alignup(sizeof(int) * N_NODES);
    int* row_ptr = (int*)p; p += alignup(sizeof(int) * N_NODES);
    float* dis   = (float*)p; p += alignup(sizeof(float) * N_NODES);
    int* bcnt    = (int*)p; p += alignup(sizeof(int) * NBUCK);
    int* bbase   = (int*)p; p += alignup(sizeof(int) * (NBUCK + 1));
    int* bcur    = (int*)p; p += alignup(sizeof(int) * NBUCK);
    int* csr     = (int*)p; p += alignup(sizeof(int) * N_EDGES);
    // union region: binned edge arrays (dead after k_csrfill) alias hs/feat
    char* U = p;
    int* bsrc = (int*)U;
    int* bdst = (int*)(U + alignup(sizeof(int) * N_EDGES));
    float* hs   = (float*)U;
    float* feat = (float*)(U + alignup(sizeof(float) * (size_t)N_NODES * HIDDEN));

    const int NB_N = (N_NODES + 255) / 256;        // 391
    const int NB_A = ((N_NODES * 32) + 255) / 256; // 12500

    hipMemsetAsync(bcnt, 0, sizeof(int) * NBUCK, stream);
    k_hist<<<BIN_BLOCKS, 256, 0, stream>>>(dstp, bcnt);
    k_bscan<<<1, 256, 0, stream>>>(bcnt, bbase, bcur);
    k_bin<<<BIN_BLOCKS, 256, 0, stream>>>(srcp, dstp, bcur, bsrc, bdst);
    k_cnt<<<NBUCK, 256, 0, stream>>>(bdst, bbase, cnt, row_ptr, dis);
    k_csrfill<<<NBUCK, NLOC, 0, stream>>>(bsrc, bdst, bbase, row_ptr, csr);

    // layer 0: in = x (128 feats), out -> feat cols [0,32)
    k_mm<128><<<NB_N, 256, 0, stream>>>(x, 0, w0, dis, hs);
    k_agg<<<NB_A, 256, 0, stream>>>(hs, dis, row_ptr, cnt, csr, b0, feat, 0);
    // layer 1
    k_mm<32><<<NB_N, 256, 0, stream>>>(feat, 0, w1, dis, hs);
    k_agg<<<NB_A, 256, 0, stream>>>(hs, dis, row_ptr, cnt, csr, b1, feat, 32);
    // layer 2
    k_mm<32><<<NB_N, 256, 0, stream>>>(feat, 32, w2, dis, hs);
    k_agg<<<NB_A, 256, 0, stream>>>(hs, dis, row_ptr, cnt, csr, b2, feat, 64);
    // layer 3
    k_mm<32><<<NB_N, 256, 0, stream>>>(feat, 64, w3, dis, hs);
    k_agg<<<NB_A, 256, 0, stream>>>(hs, dis, row_ptr, cnt, csr, b3, feat, 96);

    k_head<<<N_GRAPHS, 256, 0, stream>>>(feat, c1w, c1b, c2w, c2b,
                                         f1w, f1b, f2w, f2b, out);
}

// Round 3
// 554.420 us; speedup vs baseline: 2.1245x; 1.1887x over previous
//
#include <hip/hip_runtime.h>
#include <hip/hip_bf16.h>
#include <math.h>

#define N_NODES 100000
#define N_EDGES 3200000
#define HIDDEN 32
#define K_TOP 35
#define NPG 100
#define N_GRAPHS 1000

#define BSHIFT 9
#define NLOC 512                    // nodes per bucket
#define NBUCK 196                   // ceil(100000/512)
#define CAP 17408                   // per-bucket capacity: mean 16384 + 8 sigma
#define NBB 1024                    // bin blocks
#define BIN_CHUNK 13                // 1024*256*13 >= 3.2M

// ---------------- CSR build: single-pass binning into padded buckets ----------------

// bin edges into bucket regions [bk*CAP, bk*CAP + bcnt[bk]); packed (src<<9)|loc
__global__ void k_bin(const int* __restrict__ src, const int* __restrict__ dst,
                      int* __restrict__ bcnt, unsigned int* __restrict__ bdata) {
    __shared__ int h[NBUCK];
    __shared__ int lbase[NBUCK];
    __shared__ int lcur[NBUCK];
    int t = threadIdx.x;
    for (int i = t; i < NBUCK; i += 256) { h[i] = 0; lcur[i] = 0; }
    __syncthreads();
    int base = blockIdx.x * (256 * BIN_CHUNK);
    int ss[BIN_CHUNK], ds[BIN_CHUNK];
#pragma unroll
    for (int k = 0; k < BIN_CHUNK; k++) {
        int e = base + k * 256 + t;
        if (e < N_EDGES) {
            ss[k] = src[e];
            ds[k] = dst[e];
            atomicAdd(&h[ds[k] >> BSHIFT], 1);
        } else ds[k] = -1;
    }
    __syncthreads();
    for (int i = t; i < NBUCK; i += 256)
        lbase[i] = h[i] ? atomicAdd(&bcnt[i], h[i]) : 0;
    __syncthreads();
#pragma unroll
    for (int k = 0; k < BIN_CHUNK; k++) {
        int d = ds[k];
        if (d >= 0) {
            int bk = d >> BSHIFT;
            int pos = atomicAdd(&lcur[bk], 1);
            bdata[bk * CAP + lbase[bk] + pos] =
                ((unsigned int)ss[k] << BSHIFT) | (unsigned int)(d & (NLOC - 1));
        }
    }
}

// per-bucket node counts + within-bucket scan -> cnt, row_ptr, dis (no global scan)
__global__ void k_cnt(const unsigned int* __restrict__ bdata, const int* __restrict__ bcnt,
                      int* __restrict__ cnt, int* __restrict__ row_ptr,
                      float* __restrict__ dis) {
    __shared__ int h[NLOC];
    __shared__ int sd[256];
    int b = blockIdx.x, t = threadIdx.x;
    h[t] = 0; h[t + 256] = 0;
    __syncthreads();
    int r0 = b * CAP, r1 = r0 + bcnt[b];
    for (int i = r0 + t; i < r1; i += 256)
        atomicAdd(&h[bdata[i] & (NLOC - 1)], 1);
    __syncthreads();
    int a0 = h[2 * t], a1 = h[2 * t + 1];
    int ps = a0 + a1;
    sd[t] = ps; __syncthreads();
    for (int off = 1; off < 256; off <<= 1) {
        int x = (t >= off) ? sd[t - off] : 0;
        __syncthreads();
        sd[t] += x;
        __syncthreads();
    }
    int excl = sd[t] - ps;
    int n0 = (b << BSHIFT) + 2 * t;
    if (n0 < N_NODES) {
        cnt[n0] = a0;
        dis[n0] = rsqrtf((float)(a0 + 1));
        row_ptr[n0] = r0 + excl;
    }
    int n1 = n0 + 1;
    if (n1 < N_NODES) {
        cnt[n1] = a1;
        dis[n1] = rsqrtf((float)(a1 + 1));
        row_ptr[n1] = r0 + excl + a0;
    }
}

// per-bucket CSR fill; all writes land in one ~68KB L2-resident region
__global__ void k_csrfill(const unsigned int* __restrict__ bdata, const int* __restrict__ bcnt,
                          const int* __restrict__ row_ptr, int* __restrict__ csr) {
    __shared__ int rp[NLOC];
    __shared__ int cur[NLOC];
    int b = blockIdx.x, t = threadIdx.x;
    int node = (b << BSHIFT) + t;
    rp[t] = (node < N_NODES) ? row_ptr[node] : 0;
    cur[t] = 0;
    __syncthreads();
    int r0 = b * CAP, r1 = r0 + bcnt[b];
    for (int i = r0 + t; i < r1; i += NLOC) {
        unsigned int v = bdata[i];
        int loc = v & (NLOC - 1);
        int pos = atomicAdd(&cur[loc], 1);
        csr[rp[loc] + pos] = (int)(v >> BSHIFT);
    }
}

// ---------------- GCN layer ----------------

// hs[n][o] = dis[n] * sum_c in[n*128+col_off+c] * w[c*32+o]
template <int INF>
__global__ void k_mm(const float* __restrict__ in, int col_off,
                     const float* __restrict__ w, const float* __restrict__ dis,
                     float* __restrict__ hs) {
    __shared__ float wl[INF * HIDDEN];
    int t = threadIdx.x;
    for (int i = t; i < INF * HIDDEN; i += 256) wl[i] = w[i];
    __syncthreads();
    int n = blockIdx.x * 256 + t;
    if (n >= N_NODES) return;
    const float* row = in + (size_t)n * 128 + col_off;
    float acc[HIDDEN];
#pragma unroll
    for (int o = 0; o < HIDDEN; o++) acc[o] = 0.f;
    for (int c4 = 0; c4 < INF / 4; c4++) {
        float4 v = *(const float4*)(row + c4 * 4);
        float xv[4] = {v.x, v.y, v.z, v.w};
#pragma unroll
        for (int k = 0; k < 4; k++) {
            const float* wr = &wl[(c4 * 4 + k) * HIDDEN];
#pragma unroll
            for (int o = 0; o < HIDDEN; o++) acc[o] += xv[k] * wr[o];
        }
    }
    float d = dis[n];
    float4* o4 = (float4*)(hs + (size_t)n * HIDDEN);
#pragma unroll
    for (int q = 0; q < HIDDEN / 4; q++)
        o4[q] = make_float4(acc[4 * q] * d, acc[4 * q + 1] * d,
                            acc[4 * q + 2] * d, acc[4 * q + 3] * d);
}

// out[n][col_off+c] = tanh(dis[n]*(hs[n][c] + sum_in hs[src][c]) + b[c])
// half-wave (32 lanes) per node: 4 edge-phases x 8 channel-quads, float4 gathers
__global__ void k_agg(const float* __restrict__ hs, const float* __restrict__ dis,
                      const int* __restrict__ row_ptr, const int* __restrict__ cnt,
                      const int* __restrict__ csr_src, const float* __restrict__ bias,
                      float* __restrict__ feat, int col_off) {
    int t = blockIdx.x * 256 + threadIdx.x;
    int n = t >> 5;
    if (n >= N_NODES) return;
    int c = t & 31;
    int q = c >> 3;      // edge phase 0..3
    int r = c & 7;       // channel quad 0..7
    int start = row_ptr[n];
    int m = cnt[n];
    const float4* hs4 = (const float4*)hs;
    float ax0 = 0.f, ay0 = 0.f, az0 = 0.f, aw0 = 0.f;
    float ax1 = 0.f, ay1 = 0.f, az1 = 0.f, aw1 = 0.f;
    int j = q;
    for (; j + 4 < m; j += 8) {
        int s0 = csr_src[start + j];
        int s1 = csr_src[start + j + 4];
        float4 v0 = hs4[(size_t)s0 * 8 + r];
        float4 v1 = hs4[(size_t)s1 * 8 + r];
        ax0 += v0.x; ay0 += v0.y; az0 += v0.z; aw0 += v0.w;
        ax1 += v1.x; ay1 += v1.y; az1 += v1.z; aw1 += v1.w;
    }
    if (j < m) {
        int s0 = csr_src[start + j];
        float4 v0 = hs4[(size_t)s0 * 8 + r];
        ax0 += v0.x; ay0 += v0.y; az0 += v0.z; aw0 += v0.w;
    }
    float sx = ax0 + ax1, sy = ay0 + ay1, sz = az0 + az1, sw = aw0 + aw1;
    // reduce over the 4 edge phases (lane bits 3,4)
    sx += __shfl_xor(sx, 8);  sx += __shfl_xor(sx, 16);
    sy += __shfl_xor(sy, 8);  sy += __shfl_xor(sy, 16);
    sz += __shfl_xor(sz, 8);  sz += __shfl_xor(sz, 16);
    sw += __shfl_xor(sw, 8);  sw += __shfl_xor(sw, 16);
    if (q == 0) {
        float4 self = hs4[(size_t)n * 8 + r];
        float4 bb = ((const float4*)bias)[r];
        float d = dis[n];
        float4 o;
        o.x = tanhf(d * (sx + self.x) + bb.x);
        o.y = tanhf(d * (sy + self.y) + bb.y);
        o.z = tanhf(d * (sz + self.z) + bb.z);
        o.w = tanhf(d * (sw + self.w) + bb.w);
        *(float4*)&feat[(size_t)n * 128 + col_off + 4 * r] = o;
    }
}

// ---------------- sort-pool + head (one block per graph) ----------------

__global__ void k_head(const float* __restrict__ feat,
                       const float* __restrict__ c1w, const float* __restrict__ c1b,
                       const float* __restrict__ c2w, const float* __restrict__ c2b,
                       const float* __restrict__ f1w, const float* __restrict__ f1b,
                       const float* __restrict__ f2w, const float* __restrict__ f2b,
                       float* __restrict__ out) {
    __shared__ float vals[NPG];
    __shared__ int sel[K_TOP];
    __shared__ float tk[K_TOP][129];
    __shared__ float y1[16][K_TOP];
    __shared__ float y2[16][17];
    __shared__ float y3[416];
    __shared__ float y4[128];
    __shared__ float r2[128];
    int g = blockIdx.x, t = threadIdx.x;
    const float* fg = feat + (size_t)g * NPG * 128;

    if (t < NPG) vals[t] = fg[t * 128 + 127];
    __syncthreads();
    // stable descending rank (matches stable argsort(-v))
    if (t < NPG) {
        float v = vals[t];
        int r = 0;
        for (int j = 0; j < NPG; j++) {
            float u = vals[j];
            r += (u > v) || (u == v && j < t);
        }
        if (r < K_TOP) sel[r] = t;
    }
    __syncthreads();
    for (int i = t; i < K_TOP * 128; i += 256) {
        int k = i >> 7, c = i & 127;
        tk[k][c] = fg[sel[k] * 128 + c];
    }
    __syncthreads();
    // conv1 (1x1): y1[o][k] = relu(b + sum_c w[o,c]*tk[k][c])
    for (int i = t; i < 16 * K_TOP; i += 256) {
        int o = i & 15, k = i >> 4;
        float s = c1b[o];
        const float* wr = c1w + o * 128;
#pragma unroll 8
        for (int c = 0; c < 128; c++) s += wr[c] * tk[k][c];
        y1[o][k] = fmaxf(s, 0.f);
    }
    __syncthreads();
    // maxpool1d(2): 35 -> 17
    for (int i = t; i < 16 * 17; i += 256) {
        int o = i & 15, l = i >> 4;
        y2[o][l] = fmaxf(y1[o][2 * l], y1[o][2 * l + 1]);
    }
    __syncthreads();
    // conv2 (k=5, VALID): [16,17] -> [32,13]
    for (int idx = t; idx < 32 * 13; idx += 256) {
        int o2 = idx / 13, tt = idx - o2 * 13;
        float s = c2b[o2];
        const float* wr = c2w + o2 * 80;
#pragma unroll
        for (int i = 0; i < 16; i++)
#pragma unroll
            for (int j = 0; j < 5; j++) s += wr[i * 5 + j] * y2[i][tt + j];
        y3[idx] = fmaxf(s, 0.f);
    }
    __syncthreads();
    // fc1: 416 -> 128
    if (t < 128) {
        float s = f1b[t];
        const float* wr = f1w + t * 416;
        for (int i = 0; i < 416; i++) s += wr[i] * y3[i];
        y4[t] = fmaxf(s, 0.f);
    }
    __syncthreads();
    if (t < 128) r2[t] = f2w[t] * y4[t];
    __syncthreads();
    for (int off = 64; off > 0; off >>= 1) {
        if (t < off) r2[t] += r2[t + off];
        __syncthreads();
    }
    if (t == 0) out[g] = 1.0f / (1.0f + expf(-(r2[0] + f2b[0])));
}

// ---------------- launch ----------------

static inline size_t alignup(size_t x) { return (x + 255) & ~(size_t)255; }

extern "C" void kernel_launch(void* const* d_in, const int* in_sizes, int n_in,
                              void* d_out, int out_size, void* d_ws, size_t ws_size,
                              hipStream_t stream) {
    const float* x    = (const float*)d_in[0];
    const int*   ei   = (const int*)d_in[1];
    const int*   srcp = ei;
    const int*   dstp = ei + N_EDGES;
    const float* w0 = (const float*)d_in[3];
    const float* b0 = (const float*)d_in[4];
    const float* w1 = (const float*)d_in[5];
    const float* b1 = (const float*)d_in[6];
    const float* w2 = (const float*)d_in[7];
    const float* b2 = (const float*)d_in[8];
    const float* w3 = (const float*)d_in[9];
    const float* b3 = (const float*)d_in[10];
    const float* c1w = (const float*)d_in[11];
    const float* c1b = (const float*)d_in[12];
    const float* c2w = (const float*)d_in[13];
    const float* c2b = (const float*)d_in[14];
    const float* f1w = (const float*)d_in[15];
    const float* f1b = (const float*)d_in[16];
    const float* f2w = (const float*)d_in[17];
    const float* f2b = (const float*)d_in[18];
    float* out = (float*)d_out;

    char* p = (char*)d_ws;
    int* cnt     = (int*)p; p += alignup(sizeof(int) * N_NODES);
    int* row_ptr = (int*)p; p += alignup(sizeof(int) * N_NODES);
    float* dis   = (float*)p; p += alignup(sizeof(float) * N_NODES);
    int* bcnt    = (int*)p; p += alignup(sizeof(int) * NBUCK);
    int* csr     = (int*)p; p += alignup(sizeof(int) * (size_t)NBUCK * CAP);
    // union region: binned edge array (dead after k_csrfill) aliases hs/feat
    char* U = p;
    unsigned int* bdata = (unsigned int*)U;
    float* hs   = (float*)U;
    float* feat = (float*)(U + alignup(sizeof(float) * (size_t)N_NODES * HIDDEN));

    const int NB_N = (N_NODES + 255) / 256;        // 391
    const int NB_A = ((N_NODES * 32) + 255) / 256; // 12500

    hipMemsetAsync(bcnt, 0, sizeof(int) * NBUCK, stream);
    k_bin<<<NBB, 256, 0, stream>>>(srcp, dstp, bcnt, bdata);
    k_cnt<<<NBUCK, 256, 0, stream>>>(bdata, bcnt, cnt, row_ptr, dis);
    k_csrfill<<<NBUCK, NLOC, 0, stream>>>(bdata, bcnt, row_ptr, csr);

    // layer 0: in = x (128 feats), out -> feat cols [0,32)
    k_mm<128><<<NB_N, 256, 0, stream>>>(x, 0, w0, dis, hs);
    k_agg<<<NB_A, 256, 0, stream>>>(hs, dis, row_ptr, cnt, csr, b0, feat, 0);
    // layer 1
    k_mm<32><<<NB_N, 256, 0, stream>>>(feat, 0, w1, dis, hs);
    k_agg<<<NB_A, 256, 0, stream>>>(hs, dis, row_ptr, cnt, csr, b1, feat, 32);
    // layer 2
    k_mm<32><<<NB_N, 256, 0, stream>>>(feat, 32, w2, dis, hs);
    k_agg<<<NB_A, 256, 0, stream>>>(hs, dis, row_ptr, cnt, csr, b2, feat, 64);
    // layer 3
    k_mm<32><<<NB_N, 256, 0, stream>>>(feat, 64, w3, dis, hs);
    k_agg<<<NB_A, 256, 0, stream>>>(hs, dis, row_ptr, cnt, csr, b3, feat, 96);

    k_head<<<N_GRAPHS, 256, 0, stream>>>(feat, c1w, c1b, c2w, c2b,
                                         f1w, f1b, f2w, f2b, out);
}

// Round 4
// 481.067 us; speedup vs baseline: 2.4485x; 1.1525x over previous
//
#include <hip/hip_runtime.h>
#include <hip/hip_fp16.h>
#include <math.h>

#define N_NODES 100000
#define N_EDGES 3200000
#define HIDDEN 32
#define K_TOP 35
#define NPG 100
#define N_GRAPHS 1000

#define BSHIFT 9
#define NLOC 512                    // nodes per bucket
#define NBUCK 196                   // ceil(100000/512)
#define CAP 17408                   // per-bucket capacity: mean 16384 + 8 sigma
#define NBB 1024                    // bin blocks
#define BIN_CHUNK 13                // 1024*256*13 >= 3.2M

// ---------------- CSR build: single-pass binning into padded buckets ----------------

__global__ void k_bin(const int* __restrict__ src, const int* __restrict__ dst,
                      int* __restrict__ bcnt, unsigned int* __restrict__ bdata) {
    __shared__ int h[NBUCK];
    __shared__ int lbase[NBUCK];
    __shared__ int lcur[NBUCK];
    int t = threadIdx.x;
    for (int i = t; i < NBUCK; i += 256) { h[i] = 0; lcur[i] = 0; }
    __syncthreads();
    int base = blockIdx.x * (256 * BIN_CHUNK);
    int ss[BIN_CHUNK], ds[BIN_CHUNK];
#pragma unroll
    for (int k = 0; k < BIN_CHUNK; k++) {
        int e = base + k * 256 + t;
        if (e < N_EDGES) {
            ss[k] = src[e];
            ds[k] = dst[e];
            atomicAdd(&h[ds[k] >> BSHIFT], 1);
        } else ds[k] = -1;
    }
    __syncthreads();
    for (int i = t; i < NBUCK; i += 256)
        lbase[i] = h[i] ? atomicAdd(&bcnt[i], h[i]) : 0;
    __syncthreads();
#pragma unroll
    for (int k = 0; k < BIN_CHUNK; k++) {
        int d = ds[k];
        if (d >= 0) {
            int bk = d >> BSHIFT;
            int pos = atomicAdd(&lcur[bk], 1);
            bdata[bk * CAP + lbase[bk] + pos] =
                ((unsigned int)ss[k] << BSHIFT) | (unsigned int)(d & (NLOC - 1));
        }
    }
}

__global__ void k_cnt(const unsigned int* __restrict__ bdata, const int* __restrict__ bcnt,
                      int* __restrict__ cnt, int* __restrict__ row_ptr,
                      float* __restrict__ dis) {
    __shared__ int h[NLOC];
    __shared__ int sd[256];
    int b = blockIdx.x, t = threadIdx.x;
    h[t] = 0; h[t + 256] = 0;
    __syncthreads();
    int r0 = b * CAP, r1 = r0 + bcnt[b];
    for (int i = r0 + t; i < r1; i += 256)
        atomicAdd(&h[bdata[i] & (NLOC - 1)], 1);
    __syncthreads();
    int a0 = h[2 * t], a1 = h[2 * t + 1];
    int ps = a0 + a1;
    sd[t] = ps; __syncthreads();
    for (int off = 1; off < 256; off <<= 1) {
        int x = (t >= off) ? sd[t - off] : 0;
        __syncthreads();
        sd[t] += x;
        __syncthreads();
    }
    int excl = sd[t] - ps;
    int n0 = (b << BSHIFT) + 2 * t;
    if (n0 < N_NODES) {
        cnt[n0] = a0;
        dis[n0] = rsqrtf((float)(a0 + 1));
        row_ptr[n0] = r0 + excl;
    }
    int n1 = n0 + 1;
    if (n1 < N_NODES) {
        cnt[n1] = a1;
        dis[n1] = rsqrtf((float)(a1 + 1));
        row_ptr[n1] = r0 + excl + a0;
    }
}

__global__ void k_csrfill(const unsigned int* __restrict__ bdata, const int* __restrict__ bcnt,
                          const int* __restrict__ row_ptr, int* __restrict__ csr) {
    __shared__ int rp[NLOC];
    __shared__ int cur[NLOC];
    int b = blockIdx.x, t = threadIdx.x;
    int node = (b << BSHIFT) + t;
    rp[t] = (node < N_NODES) ? row_ptr[node] : 0;
    cur[t] = 0;
    __syncthreads();
    int r0 = b * CAP, r1 = r0 + bcnt[b];
    for (int i = r0 + t; i < r1; i += NLOC) {
        unsigned int v = bdata[i];
        int loc = v & (NLOC - 1);
        int pos = atomicAdd(&cur[loc], 1);
        csr[rp[loc] + pos] = (int)(v >> BSHIFT);
    }
}

// ---------------- GCN layer ----------------

// layer 0: hs[n][o] (fp16) = dis[n] * sum_c x[n*128+c] * w[c*32+o]
__global__ void k_mm0(const float* __restrict__ in, const float* __restrict__ w,
                      const float* __restrict__ dis, void* __restrict__ hs) {
    __shared__ float wl[128 * HIDDEN];
    int t = threadIdx.x;
    for (int i = t; i < 128 * HIDDEN; i += 256) wl[i] = w[i];
    __syncthreads();
    int n = blockIdx.x * 256 + t;
    if (n >= N_NODES) return;
    const float* row = in + (size_t)n * 128;
    float acc[HIDDEN];
#pragma unroll
    for (int o = 0; o < HIDDEN; o++) acc[o] = 0.f;
    for (int c4 = 0; c4 < 32; c4++) {
        float4 v = *(const float4*)(row + c4 * 4);
        float xv[4] = {v.x, v.y, v.z, v.w};
#pragma unroll
        for (int k = 0; k < 4; k++) {
            const float* wr = &wl[(c4 * 4 + k) * HIDDEN];
#pragma unroll
            for (int o = 0; o < HIDDEN; o++) acc[o] += xv[k] * wr[o];
        }
    }
    float d = dis[n];
    float4* hr = (float4*)((char*)hs + (size_t)n * 64);
#pragma unroll
    for (int qq = 0; qq < 4; qq++) {
        __half2 p[4];
#pragma unroll
        for (int k = 0; k < 4; k++)
            p[k] = __floats2half2_rn(acc[8 * qq + 2 * k] * d, acc[8 * qq + 2 * k + 1] * d);
        hr[qq] = *(float4*)p;
    }
}

// fused: aggregate (fp16 gather) + tanh + feat write + next-layer matvec -> hs_next (fp16)
// half-wave (32 lanes) per node: 8 edge-phases (q) x 4 half2-quads (r)
__global__ void k_agg(const float4* __restrict__ hs4, const float* __restrict__ dis,
                      const int* __restrict__ row_ptr, const int* __restrict__ cnt,
                      const int* __restrict__ csr_src, const float* __restrict__ bias,
                      float* __restrict__ feat, int col_off,
                      const float* __restrict__ wnext, void* __restrict__ hsn) {
    __shared__ float wl[32 * 33];
    __shared__ float tv[8][36];
    int tt = threadIdx.x;
    if (wnext) {
        for (int i = tt; i < 1024; i += 256)
            wl[(i >> 5) * 33 + (i & 31)] = wnext[i];
    }
    __syncthreads();
    int n = (blockIdx.x * 256 + tt) >> 5;   // grid covers exactly N_NODES*32 lanes
    int c = tt & 31;
    int q = c >> 2, r = c & 3;
    int start = row_ptr[n];
    int m = cnt[n];
    float a0=0,a1=0,a2=0,a3=0,a4=0,a5=0,a6=0,a7=0;
    float b0=0,b1=0,b2=0,b3=0,b4=0,b5=0,b6=0,b7=0;
    int j = q;
    for (; j + 8 < m; j += 16) {
        int s0 = csr_src[start + j];
        int s1 = csr_src[start + j + 8];
        float4 v0 = hs4[(size_t)s0 * 4 + r];
        float4 v1 = hs4[(size_t)s1 * 4 + r];
        const __half2* h0 = (const __half2*)&v0;
        const __half2* h1 = (const __half2*)&v1;
        float2 f;
        f = __half22float2(h0[0]); a0 += f.x; a1 += f.y;
        f = __half22float2(h0[1]); a2 += f.x; a3 += f.y;
        f = __half22float2(h0[2]); a4 += f.x; a5 += f.y;
        f = __half22float2(h0[3]); a6 += f.x; a7 += f.y;
        f = __half22float2(h1[0]); b0 += f.x; b1 += f.y;
        f = __half22float2(h1[1]); b2 += f.x; b3 += f.y;
        f = __half22float2(h1[2]); b4 += f.x; b5 += f.y;
        f = __half22float2(h1[3]); b6 += f.x; b7 += f.y;
    }
    if (j < m) {
        int s0 = csr_src[start + j];
        float4 v0 = hs4[(size_t)s0 * 4 + r];
        const __half2* h0 = (const __half2*)&v0;
        float2 f;
        f = __half22float2(h0[0]); a0 += f.x; a1 += f.y;
        f = __half22float2(h0[1]); a2 += f.x; a3 += f.y;
        f = __half22float2(h0[2]); a4 += f.x; a5 += f.y;
        f = __half22float2(h0[3]); a6 += f.x; a7 += f.y;
    }
    float s[8];
    s[0]=a0+b0; s[1]=a1+b1; s[2]=a2+b2; s[3]=a3+b3;
    s[4]=a4+b4; s[5]=a5+b5; s[6]=a6+b6; s[7]=a7+b7;
#pragma unroll
    for (int k = 0; k < 8; k++) {
        float v = s[k];
        v += __shfl_xor(v, 4);
        v += __shfl_xor(v, 8);
        v += __shfl_xor(v, 16);
        s[k] = v;
    }
    float d = dis[n];
    int slot = tt >> 5;
    if (q == 0) {
        float4 sv = hs4[(size_t)n * 4 + r];
        const __half2* sh = (const __half2*)&sv;
        const float* bb = bias + 8 * r;
        float ov[8];
#pragma unroll
        for (int k = 0; k < 4; k++) {
            float2 f = __half22float2(sh[k]);
            ov[2 * k]     = tanhf(d * (s[2 * k]     + f.x) + bb[2 * k]);
            ov[2 * k + 1] = tanhf(d * (s[2 * k + 1] + f.y) + bb[2 * k + 1]);
        }
        float* fr = feat + (size_t)n * 128 + col_off + 8 * r;
        *(float4*)fr       = make_float4(ov[0], ov[1], ov[2], ov[3]);
        *(float4*)(fr + 4) = make_float4(ov[4], ov[5], ov[6], ov[7]);
        if (wnext) {
            *(float4*)&tv[slot][8 * r]     = make_float4(ov[0], ov[1], ov[2], ov[3]);
            *(float4*)&tv[slot][8 * r + 4] = make_float4(ov[4], ov[5], ov[6], ov[7]);
        }
    }
    if (wnext) {
        __builtin_amdgcn_wave_barrier();   // keep tv writes before reads (same wave, DS in-order)
        float o = 0.f;
#pragma unroll 8
        for (int k = 0; k < 32; k++)
            o += tv[slot][k] * wl[k * 33 + c];
        o *= d;
        float oh = __shfl_xor(o, 1);
        if ((c & 1) == 0) {
            __half2 p = __floats2half2_rn(o, oh);
            *((__half2*)((char*)hsn + (size_t)n * 64 + 2 * c)) = p;
        }
    }
}

// ---------------- sort-pool + head (one block per graph) ----------------

__global__ void __launch_bounds__(256, 4)
k_head(const float* __restrict__ feat,
       const float* __restrict__ c1w, const float* __restrict__ c1b,
       const float* __restrict__ c2w, const float* __restrict__ c2b,
       const float* __restrict__ f1w, const float* __restrict__ f1b,
       const float* __restrict__ f2w, const float* __restrict__ f2b,
       float* __restrict__ out) {
    __shared__ float vals[NPG];
    __shared__ int sel[K_TOP];
    __shared__ float tk[K_TOP * 132];
    __shared__ float wl1[16 * 129];
    __shared__ float y1[16][36];
    __shared__ float y2[16][17];
    __shared__ float y3[416];
    __shared__ float y4[128];
    __shared__ float r2[128];
    int g = blockIdx.x, t = threadIdx.x;
    const float* fg = feat + (size_t)g * NPG * 128;

    for (int i = t; i < 2048; i += 256)
        wl1[(i >> 7) * 129 + (i & 127)] = c1w[i];
    if (t < NPG) vals[t] = fg[t * 128 + 127];
    __syncthreads();
    // stable descending rank (matches stable argsort(-v))
    if (t < NPG) {
        float v = vals[t];
        int r = 0;
        for (int j = 0; j < NPG; j++) {
            float u = vals[j];
            r += (u > v) || (u == v && j < t);
        }
        if (r < K_TOP) sel[r] = t;
    }
    __syncthreads();
    for (int i = t; i < K_TOP * 32; i += 256) {
        int k = i >> 5, c4 = i & 31;
        *(float4*)&tk[k * 132 + 4 * c4] = *(const float4*)&fg[sel[k] * 128 + 4 * c4];
    }
    __syncthreads();
    // conv1 (1x1), weights from LDS
    for (int i = t; i < 16 * K_TOP; i += 256) {
        int o = i & 15, k = i >> 4;
        float s = c1b[o];
        const float* wr = &wl1[o * 129];
        const float* xr = &tk[k * 132];
#pragma unroll 8
        for (int c = 0; c < 128; c++) s += wr[c] * xr[c];
        y1[o][k] = fmaxf(s, 0.f);
    }
    __syncthreads();
    // maxpool1d(2): 35 -> 17
    for (int i = t; i < 16 * 17; i += 256) {
        int o = i & 15, l = i >> 4;
        y2[o][l] = fmaxf(y1[o][2 * l], y1[o][2 * l + 1]);
    }
    __syncthreads();
    // conv2 (k=5, VALID): [16,17] -> [32,13]
    for (int idx = t; idx < 32 * 13; idx += 256) {
        int o2 = idx / 13, ttp = idx - o2 * 13;
        float s = c2b[o2];
        const float* wr = c2w + o2 * 80;
#pragma unroll
        for (int i = 0; i < 16; i++)
#pragma unroll
            for (int j = 0; j < 5; j++) s += wr[i * 5 + j] * y2[i][ttp + j];
        y3[idx] = fmaxf(s, 0.f);
    }
    __syncthreads();
    // fc1: 416 -> 128, 2 threads per output, float4 weight loads
    {
        int o = t >> 1, h = t & 1;
        const float4* wr4 = (const float4*)(f1w + o * 416) + h * 52;
        const float* yb = y3 + h * 208;
        float s = 0.f;
#pragma unroll 4
        for (int i = 0; i < 52; i++) {
            float4 w4 = wr4[i];
            s += w4.x * yb[4 * i] + w4.y * yb[4 * i + 1] +
                 w4.z * yb[4 * i + 2] + w4.w * yb[4 * i + 3];
        }
        s += __shfl_xor(s, 1);
        if (h == 0) y4[o] = fmaxf(s + f1b[o], 0.f);
    }
    __syncthreads();
    if (t < 128) r2[t] = f2w[t] * y4[t];
    __syncthreads();
    for (int off = 64; off > 0; off >>= 1) {
        if (t < off) r2[t] += r2[t + off];
        __syncthreads();
    }
    if (t == 0) out[g] = 1.0f / (1.0f + expf(-(r2[0] + f2b[0])));
}

// ---------------- launch ----------------

static inline size_t alignup(size_t x) { return (x + 255) & ~(size_t)255; }

extern "C" void kernel_launch(void* const* d_in, const int* in_sizes, int n_in,
                              void* d_out, int out_size, void* d_ws, size_t ws_size,
                              hipStream_t stream) {
    const float* x    = (const float*)d_in[0];
    const int*   ei   = (const int*)d_in[1];
    const int*   srcp = ei;
    const int*   dstp = ei + N_EDGES;
    const float* w0 = (const float*)d_in[3];
    const float* b0 = (const float*)d_in[4];
    const float* w1 = (const float*)d_in[5];
    const float* b1 = (const float*)d_in[6];
    const float* w2 = (const float*)d_in[7];
    const float* b2 = (const float*)d_in[8];
    const float* w3 = (const float*)d_in[9];
    const float* b3 = (const float*)d_in[10];
    const float* c1w = (const float*)d_in[11];
    const float* c1b = (const float*)d_in[12];
    const float* c2w = (const float*)d_in[13];
    const float* c2b = (const float*)d_in[14];
    const float* f1w = (const float*)d_in[15];
    const float* f1b = (const float*)d_in[16];
    const float* f2w = (const float*)d_in[17];
    const float* f2b = (const float*)d_in[18];
    float* out = (float*)d_out;

    char* p = (char*)d_ws;
    int* cnt     = (int*)p; p += alignup(sizeof(int) * N_NODES);
    int* row_ptr = (int*)p; p += alignup(sizeof(int) * N_NODES);
    float* dis   = (float*)p; p += alignup(sizeof(float) * N_NODES);
    int* bcnt    = (int*)p; p += alignup(sizeof(int) * NBUCK);
    int* csr     = (int*)p; p += alignup(sizeof(int) * (size_t)NBUCK * CAP);
    // union region: bdata (dead after k_csrfill) aliases the two fp16 hs buffers
    char* U = p;
    unsigned int* bdata = (unsigned int*)U;
    void* hsA = (void*)U;                                          // 6.4 MB fp16
    void* hsB = (void*)(U + alignup((size_t)N_NODES * 64));        // 6.4 MB fp16
    size_t usz = alignup(sizeof(unsigned int) * (size_t)NBUCK * CAP); // 13.65 MB > 12.8
    float* feat = (float*)(U + usz);

    const int NB_N = (N_NODES + 255) / 256;        // 391
    const int NB_A = (N_NODES * 32) / 256;         // 12500 (exact)

    hipMemsetAsync(bcnt, 0, sizeof(int) * NBUCK, stream);
    k_bin<<<NBB, 256, 0, stream>>>(srcp, dstp, bcnt, bdata);
    k_cnt<<<NBUCK, 256, 0, stream>>>(bdata, bcnt, cnt, row_ptr, dis);
    k_csrfill<<<NBUCK, NLOC, 0, stream>>>(bdata, bcnt, row_ptr, csr);

    k_mm0<<<NB_N, 256, 0, stream>>>(x, w0, dis, hsA);
    k_agg<<<NB_A, 256, 0, stream>>>((const float4*)hsA, dis, row_ptr, cnt, csr, b0,
                                    feat, 0, w1, hsB);
    k_agg<<<NB_A, 256, 0, stream>>>((const float4*)hsB, dis, row_ptr, cnt, csr, b1,
                                    feat, 32, w2, hsA);
    k_agg<<<NB_A, 256, 0, stream>>>((const float4*)hsA, dis, row_ptr, cnt, csr, b2,
                                    feat, 64, w3, hsB);
    k_agg<<<NB_A, 256, 0, stream>>>((const float4*)hsB, dis, row_ptr, cnt, csr, b3,
                                    feat, 96, (const float*)nullptr, (void*)nullptr);

    k_head<<<N_GRAPHS, 256, 0, stream>>>(feat, c1w, c1b, c2w, c2b,
                                         f1w, f1b, f2w, f2b, out);
}